// Round 8
// baseline (3036.401 us; speedup 1.0000x reference)
//
#include <hip/hip_runtime.h>

#define HOUT 15
#define WOUT 15
// input  (32, 32, 32, 32, 16)  fp32   n-stride 16384 floats
// ncv    (32, 32, 15, 15, 16)  fp32
// w      (3, 3, 32, 4, 4, 32)  fp32   strides: kl 16384, n 512, xd 32, m 1
// out    (32, 32, 15, 15, 16)  fp32

typedef float v2 __attribute__((ext_vector_type(2)));

// ---------------- pass 0: transpose w -> wT[n][kl][m][16] ------------------
__global__ __launch_bounds__(256) void w_transpose(
    const float* __restrict__ wt, float* __restrict__ wT)
{
    const int t = blockIdx.x * 256 + threadIdx.x;   // 0..9215
    const int n  = t / 288;
    const int r  = t % 288;
    const int kl = r >> 5;
    const int m  = r & 31;

    const float* src = wt + kl * 16384 + n * 512 + m;
    float v[16];
#pragma unroll
    for (int xd = 0; xd < 16; ++xd) v[xd] = src[xd * 32];

    float* dst = wT + (size_t)t * 16;
#pragma unroll
    for (int j = 0; j < 4; ++j) {
        float4 o = {v[4 * j], v[4 * j + 1], v[4 * j + 2], v[4 * j + 3]};
        *(float4*)(dst + 4 * j) = o;
    }
}

// ---------------- pass 1: fused, half-wave n-split, SW-pipelined -----------
// One 64-lane wave per output position; lane&31 = m; half-waves split n
// (0..15 / 16..31), combined at the end via __shfl_xor(...,32). The (n,kl)
// loop is explicitly software-pipelined: next iteration's 8 VMEM loads
// (w-row + input tile) are issued into double-buffer registers BEFORE the
// current compute. Round 7 showed the compiler otherwise register-minimizes
// to 52 VGPRs and serializes the loads (~1600 cyc/iter latency).
__global__ __launch_bounds__(256, 2) void caps_fused(
    const float* __restrict__ input,
    const float* __restrict__ ncv,
    const float* __restrict__ wT,
    const float* __restrict__ gamma,
    const float* __restrict__ beta,
    float* __restrict__ out)
{
    const int tid  = threadIdx.x;
    const int grp  = tid >> 6;          // wave id 0..3 = position
    const int lane = tid & 31;          // m
    const int n0   = (tid & 32) >> 1;   // 0 | 16

    const int pos = blockIdx.x * 4 + grp;   // 0..7199
    const int b   = pos / (HOUT * WOUT);
    const int hw  = pos % (HOUT * WOUT);
    const int h   = hw / WOUT;
    const int wo  = hw % WOUT;

    const float* ncv_p = ncv + ((((size_t)b * 32 + lane) * HOUT + h) * WOUT + wo) * 16;
    v2 cv2[8];
#pragma unroll
    for (int j = 0; j < 8; ++j) cv2[j] = *(const v2*)(ncv_p + j * 2);

    v2 acc2[8];
#pragma unroll
    for (int j = 0; j < 8; ++j) acc2[j] = (v2){0.0f, 0.0f};

    const int h0 = h * 2, w0 = wo * 2;
    // av tile offsets for kl = 0..8  ((k*32+l)*16)
    const int off[9] = {0, 16, 32, 512, 528, 544, 1024, 1040, 1056};

    const float* ipn = input + ((((size_t)b * 32 + n0) * 32 + h0) * 32 + w0) * 16;
    const float* wn  = wT + ((size_t)n0 * 288 + lane) * 16;

    // double-buffered pipeline registers: w-row (16f) + input tile (16f)
    float wvb[2][16];
    float avb[2][16];

    // preload slot 0 : (i=0, kl=0)
#pragma unroll
    for (int x = 0; x < 4; ++x) {
        *(float4*)&wvb[0][4 * x] = *(const float4*)(wn + 4 * x);
        *(float4*)&avb[0][4 * x] = *(const float4*)(ipn + 4 * x);
    }

    int p = 0;
    for (int i = 0; i < 16; ++i) {
        const float* ipn_n = ipn + 16384;   // next n: input n-stride
        const float* wn_n  = wn + 4608;     // next n: wT n-stride (288*16)

#pragma unroll
        for (int kl = 0; kl < 9; ++kl) {
            // ---- prefetch next (n,kl) into the other buffer ----
            if (kl < 8) {
                const float* nwr = wn + (kl + 1) * 512;
                const float* nip = ipn + off[kl + 1];
#pragma unroll
                for (int x = 0; x < 4; ++x) {
                    *(float4*)&wvb[p ^ 1][4 * x] = *(const float4*)(nwr + 4 * x);
                    *(float4*)&avb[p ^ 1][4 * x] = *(const float4*)(nip + 4 * x);
                }
            } else if (i < 15) {
#pragma unroll
                for (int x = 0; x < 4; ++x) {
                    *(float4*)&wvb[p ^ 1][4 * x] = *(const float4*)(wn_n + 4 * x);
                    *(float4*)&avb[p ^ 1][4 * x] = *(const float4*)(ipn_n + 4 * x);
                }
            }

            // ---- compute current iteration from buffer p ----
            const float* wv = wvb[p];
            const float* av = avb[p];

            v2 u2[8];
#pragma unroll
            for (int j = 0; j < 8; ++j) u2[j] = (v2){0.0f, 0.0f};
#pragma unroll
            for (int x = 0; x < 4; ++x) {
                v2 wlo = {wv[4 * x + 0], wv[4 * x + 1]};
                v2 whi = {wv[4 * x + 2], wv[4 * x + 3]};
#pragma unroll
                for (int a = 0; a < 4; ++a) {
                    v2 sp = {av[a * 4 + x], av[a * 4 + x]};
                    u2[a * 2 + 0] = __builtin_elementwise_fma(sp, wlo, u2[a * 2 + 0]);
                    u2[a * 2 + 1] = __builtin_elementwise_fma(sp, whi, u2[a * 2 + 1]);
                }
            }

            // logit = 0.25 * <u, cv>
            v2 d0 = {0.f, 0.f}, d1 = {0.f, 0.f};
#pragma unroll
            for (int j = 0; j < 4; ++j) {
                d0 = __builtin_elementwise_fma(u2[j],     cv2[j],     d0);
                d1 = __builtin_elementwise_fma(u2[j + 4], cv2[j + 4], d1);
            }
            v2 dd = d0 + d1;
            float logit = (dd.x + dd.y) * 0.25f;

            // softmax over m (32 lanes within this half-wave)
            float e = __expf(logit);
            float sum = e;
#pragma unroll
            for (int o = 16; o > 0; o >>= 1)
                sum += __shfl_xor(sum, o, 32);
            float pr = e * __builtin_amdgcn_rcpf(sum);
            v2 p2 = {pr, pr};

#pragma unroll
            for (int j = 0; j < 8; ++j)
                acc2[j] = __builtin_elementwise_fma(p2, u2[j], acc2[j]);

            p ^= 1;
        }

        ipn = ipn_n;
        wn  = wn_n;
    }

    // combine the two half-waves' partial sums (register-only)
#pragma unroll
    for (int j = 0; j < 8; ++j) {
        acc2[j].x += __shfl_xor(acc2[j].x, 32, 64);
        acc2[j].y += __shfl_xor(acc2[j].y, 32, 64);
    }

    // LayerNorm (redundant in both halves; each stores its 8-float half)
    float a[16];
#pragma unroll
    for (int j = 0; j < 8; ++j) { a[2 * j] = acc2[j].x; a[2 * j + 1] = acc2[j].y; }

    float mu = 0.0f;
#pragma unroll
    for (int j = 0; j < 16; ++j) mu += a[j];
    mu *= 0.0625f;
    float var = 0.0f;
#pragma unroll
    for (int j = 0; j < 16; ++j) { float d = a[j] - mu; var = fmaf(d, d, var); }
    var *= 0.0625f;
    float rstd = __builtin_amdgcn_rsqf(var + 1e-5f);

    const int d8 = (tid & 32) >> 2;     // 0 | 8
    float* op = out + ((((size_t)b * 32 + lane) * HOUT + h) * WOUT + wo) * 16 + d8;
#pragma unroll
    for (int j = 0; j < 8; j += 4) {
        float4 g  = *(const float4*)(gamma + d8 + j);
        float4 be = *(const float4*)(beta + d8 + j);
        float4 r;
        r.x = (a[d8 + j + 0] - mu) * rstd * g.x + be.x;
        r.y = (a[d8 + j + 1] - mu) * rstd * g.y + be.y;
        r.z = (a[d8 + j + 2] - mu) * rstd * g.z + be.z;
        r.w = (a[d8 + j + 3] - mu) * rstd * g.w + be.w;
        *(float4*)(op + j) = r;
    }
}

extern "C" void kernel_launch(void* const* d_in, const int* in_sizes, int n_in,
                              void* d_out, int out_size, void* d_ws, size_t ws_size,
                              hipStream_t stream) {
    const float* input = (const float*)d_in[0];
    const float* ncv   = (const float*)d_in[1];
    const float* wt    = (const float*)d_in[2];
    const float* gamma = (const float*)d_in[3];
    const float* beta  = (const float*)d_in[4];
    float* out = (float*)d_out;
    float* wT  = (float*)d_ws;     // 147456 floats = 589 KB

    w_transpose<<<dim3(36), dim3(256), 0, stream>>>(wt, wT);
    caps_fused<<<dim3(1800), dim3(256), 0, stream>>>(input, ncv, wT, gamma, beta, out);
}

// Round 9
// 489.682 us; speedup vs baseline: 6.2008x; 6.2008x over previous
//
#include <hip/hip_runtime.h>

#define HOUT 15
#define WOUT 15
// input  (32, 32, 32, 32, 16)  fp32   n-stride 16384 floats
// ncv    (32, 32, 15, 15, 16)  fp32
// w      (3, 3, 32, 4, 4, 32)  fp32   strides: kl 16384, n 512, xd 32, m 1
// out    (32, 32, 15, 15, 16)  fp32
// wT     [n][kl][m][16]: n-stride 4608, kl-stride 512, m-stride 16

typedef float v2 __attribute__((ext_vector_type(2)));

// ---------------- pass 0: transpose w -> wT[n][kl][m][16] ------------------
__global__ __launch_bounds__(256) void w_transpose(
    const float* __restrict__ wt, float* __restrict__ wT)
{
    const int t = blockIdx.x * 256 + threadIdx.x;   // 0..9215
    const int n  = t / 288;
    const int r  = t % 288;
    const int kl = r >> 5;
    const int m  = r & 31;

    const float* src = wt + kl * 16384 + n * 512 + m;
    float v[16];
#pragma unroll
    for (int xd = 0; xd < 16; ++xd) v[xd] = src[xd * 32];

    float* dst = wT + (size_t)t * 16;
#pragma unroll
    for (int j = 0; j < 4; ++j) {
        float4 o = {v[4 * j], v[4 * j + 1], v[4 * j + 2], v[4 * j + 3]};
        *(float4*)(dst + 4 * j) = o;
    }
}

// ---------------- pass 1: fused, half-wave n-split, static SW pipeline -----
// One 64-lane wave per output position; lane&31 = m; half-waves split n
// (0..15 / 16..31), combined at the end via __shfl_xor(...,32).
// Pipeline: outer loop of 8 iterations, each covering TWO n values = 18
// fully-unrolled stages, so the double-buffer index (s&1) is compile-time
// (round 8's runtime-indexed buffers were demoted to scratch -> 7.4 GB of
// spill traffic). Stage s computes buf[s&1] then re-issues its 8 dwordx4
// loads for stage s+2 -> distance-2 in-flight, WAR-ordered after last use.
__global__ __launch_bounds__(256, 2) void caps_fused(
    const float* __restrict__ input,
    const float* __restrict__ ncv,
    const float* __restrict__ wT,
    const float* __restrict__ gamma,
    const float* __restrict__ beta,
    float* __restrict__ out)
{
    const int tid  = threadIdx.x;
    const int grp  = tid >> 6;          // wave id 0..3 = position
    const int lane = tid & 31;          // m
    const int n0   = (tid & 32) >> 1;   // 0 | 16

    const int pos = blockIdx.x * 4 + grp;   // 0..7199
    const int b   = pos / (HOUT * WOUT);
    const int hw  = pos % (HOUT * WOUT);
    const int h   = hw / WOUT;
    const int wo  = hw % WOUT;

    const float* ncv_p = ncv + ((((size_t)b * 32 + lane) * HOUT + h) * WOUT + wo) * 16;
    v2 cv2[8];
#pragma unroll
    for (int j = 0; j < 8; ++j) cv2[j] = *(const v2*)(ncv_p + j * 2);

    v2 acc2[8];
#pragma unroll
    for (int j = 0; j < 8; ++j) acc2[j] = (v2){0.0f, 0.0f};

    const int h0 = h * 2, w0 = wo * 2;

    // per-half-wave base pointers (advance by 2 n per outer iteration)
    const float* ip_ii = input + ((((size_t)b * 32 + n0) * 32 + h0) * 32 + w0) * 16;
    const float* w_ii  = wT + (size_t)n0 * 4608 + lane * 16;

    float4 bw[2][4];   // w-row double buffer   (all indices compile-time)
    float4 ba[2][4];   // input-tile double buffer

    // preload stages 0 (n local 0, kl 0) and 1 (n local 0, kl 1)
#pragma unroll
    for (int x = 0; x < 4; ++x) {
        bw[0][x] = *(const float4*)(w_ii + 4 * x);
        ba[0][x] = *(const float4*)(ip_ii + 4 * x);
        bw[1][x] = *(const float4*)(w_ii + 512 + 4 * x);
        ba[1][x] = *(const float4*)(ip_ii + 16 + 4 * x);
    }

#pragma unroll 1
    for (int ii = 0; ii < 8; ++ii) {
        // clamp the cross-block prefetch for the last outer iteration:
        // redundant in-bounds reload instead of a branch / OOB access.
        const size_t dW2 = (ii < 7) ? (size_t)(2 * 4608)  : 0;
        const size_t dA2 = (ii < 7) ? (size_t)(2 * 16384) : 0;

#pragma unroll
        for (int s = 0; s < 18; ++s) {
            const int cur = s & 1;

            // ---- compute stage s from bw[cur]/ba[cur] ----
            v2 u2[8];
#pragma unroll
            for (int j = 0; j < 8; ++j) u2[j] = (v2){0.0f, 0.0f};
#pragma unroll
            for (int x = 0; x < 4; ++x) {
                v2 wlo = {bw[cur][x].x, bw[cur][x].y};
                v2 whi = {bw[cur][x].z, bw[cur][x].w};
                const float4 at = ba[cur][x];   // av[a=x][0..3] is at x? no:
                // ba[cur][q] holds av[4q..4q+3]; need av[a*4+x] per (a,x).
                (void)at;
            }
            // unpack input tile to scalars first (av[j] = element j)
            float av[16];
#pragma unroll
            for (int q = 0; q < 4; ++q) {
                av[4 * q + 0] = ba[cur][q].x;
                av[4 * q + 1] = ba[cur][q].y;
                av[4 * q + 2] = ba[cur][q].z;
                av[4 * q + 3] = ba[cur][q].w;
            }
#pragma unroll
            for (int x = 0; x < 4; ++x) {
                v2 wlo = {bw[cur][x].x, bw[cur][x].y};
                v2 whi = {bw[cur][x].z, bw[cur][x].w};
#pragma unroll
                for (int a = 0; a < 4; ++a) {
                    v2 sp = {av[a * 4 + x], av[a * 4 + x]};
                    u2[a * 2 + 0] = __builtin_elementwise_fma(sp, wlo, u2[a * 2 + 0]);
                    u2[a * 2 + 1] = __builtin_elementwise_fma(sp, whi, u2[a * 2 + 1]);
                }
            }

            // ---- prefetch stage g = s+2 into the SAME buffer (WAR-safe) ----
            {
                const int g   = s + 2;            // 2..19, all compile-time
                const int gn  = g / 9;            // 0,1,2
                const int gkl = g % 9;
                const size_t wOff = (gn < 2 ? (size_t)gn * 4608  : dW2) + (size_t)gkl * 512;
                const size_t aOff = (gn < 2 ? (size_t)gn * 16384 : dA2)
                                  + (size_t)((gkl / 3) * 512 + (gkl % 3) * 16);
#pragma unroll
                for (int x = 0; x < 4; ++x) {
                    bw[cur][x] = *(const float4*)(w_ii + wOff + 4 * x);
                    ba[cur][x] = *(const float4*)(ip_ii + aOff + 4 * x);
                }
            }

            // ---- rest of stage s (independent of the buffers) ----
            // logit = 0.25 * <u, cv>
            v2 d0 = {0.f, 0.f}, d1 = {0.f, 0.f};
#pragma unroll
            for (int j = 0; j < 4; ++j) {
                d0 = __builtin_elementwise_fma(u2[j],     cv2[j],     d0);
                d1 = __builtin_elementwise_fma(u2[j + 4], cv2[j + 4], d1);
            }
            v2 dd = d0 + d1;
            float logit = (dd.x + dd.y) * 0.25f;

            // softmax over m (32 lanes within this half-wave); no max-subtract
            float e = __expf(logit);
            float sum = e;
#pragma unroll
            for (int o = 16; o > 0; o >>= 1)
                sum += __shfl_xor(sum, o, 32);
            float pr = e * __builtin_amdgcn_rcpf(sum);
            v2 p2 = {pr, pr};

#pragma unroll
            for (int j = 0; j < 8; ++j)
                acc2[j] = __builtin_elementwise_fma(p2, u2[j], acc2[j]);
        }

        ip_ii += 2 * 16384;
        w_ii  += 2 * 4608;
    }

    // combine the two half-waves' partial sums (register-only)
#pragma unroll
    for (int j = 0; j < 8; ++j) {
        acc2[j].x += __shfl_xor(acc2[j].x, 32, 64);
        acc2[j].y += __shfl_xor(acc2[j].y, 32, 64);
    }

    // LayerNorm (redundant in both halves; each stores its 8-float half)
    float a[16];
#pragma unroll
    for (int j = 0; j < 8; ++j) { a[2 * j] = acc2[j].x; a[2 * j + 1] = acc2[j].y; }

    float mu = 0.0f;
#pragma unroll
    for (int j = 0; j < 16; ++j) mu += a[j];
    mu *= 0.0625f;
    float var = 0.0f;
#pragma unroll
    for (int j = 0; j < 16; ++j) { float d = a[j] - mu; var = fmaf(d, d, var); }
    var *= 0.0625f;
    float rstd = __builtin_amdgcn_rsqf(var + 1e-5f);

    const int d8 = (tid & 32) >> 2;     // 0 | 8
    float* op = out + ((((size_t)b * 32 + lane) * HOUT + h) * WOUT + wo) * 16 + d8;
#pragma unroll
    for (int j = 0; j < 8; j += 4) {
        float4 g  = *(const float4*)(gamma + d8 + j);
        float4 be = *(const float4*)(beta + d8 + j);
        float4 r;
        r.x = (a[d8 + j + 0] - mu) * rstd * g.x + be.x;
        r.y = (a[d8 + j + 1] - mu) * rstd * g.y + be.y;
        r.z = (a[d8 + j + 2] - mu) * rstd * g.z + be.z;
        r.w = (a[d8 + j + 3] - mu) * rstd * g.w + be.w;
        *(float4*)(op + j) = r;
    }
}

extern "C" void kernel_launch(void* const* d_in, const int* in_sizes, int n_in,
                              void* d_out, int out_size, void* d_ws, size_t ws_size,
                              hipStream_t stream) {
    const float* input = (const float*)d_in[0];
    const float* ncv   = (const float*)d_in[1];
    const float* wt    = (const float*)d_in[2];
    const float* gamma = (const float*)d_in[3];
    const float* beta  = (const float*)d_in[4];
    float* out = (float*)d_out;
    float* wT  = (float*)d_ws;     // 147456 floats = 589 KB

    w_transpose<<<dim3(36), dim3(256), 0, stream>>>(wt, wT);
    caps_fused<<<dim3(1800), dim3(256), 0, stream>>>(input, ncv, wT, gamma, beta, out);
}